// Round 6
// baseline (212.054 us; speedup 1.0000x reference)
//
#include <hip/hip_runtime.h>

// Problem constants: B=128, P=2048, N=256, D=2
constexpr int B   = 128;
constexpr int P   = 2048;
constexpr int N   = 256;
constexpr int TPB = 256;   // 4 waves
constexpr int NPB = 8;     // centers per block
constexpr int KQ  = 4;     // float4 loads per lane = 8 points/lane

__device__ __forceinline__ float rdfl(float v) {
    return __int_as_float(__builtin_amdgcn_readfirstlane(__float_as_int(v)));
}

// ---------------- Kernel A: real output (R5 verbatim) ----------------
__global__ __launch_bounds__(TPB, 8)
void SLayerRational_43190191128606_kernel(
    const float* __restrict__ batch,      // (B, P, 2)
    const float* __restrict__ not_dummy,  // (B, P)
    const float* __restrict__ centers,    // (N, 2)
    const float* __restrict__ sharpness,  // (N, 2)
    const float* __restrict__ exponent,   // (1,)
    float* __restrict__ out)              // (B, N)
{
    const int b    = blockIdx.x >> 5;
    const int n0   = (blockIdx.x & 31) * NPB;
    const int wave = threadIdx.x >> 6;
    const int lane = threadIdx.x & 63;

    float c0[NPB], c1[NPB], a0[NPB], a1[NPB];
#pragma unroll
    for (int c = 0; c < NPB; ++c) {
        c0[c] = rdfl(centers[(n0 + c) * 2 + 0]);
        c1[c] = rdfl(centers[(n0 + c) * 2 + 1]);
        a0[c] = rdfl(fabsf(sharpness[(n0 + c) * 2 + 0]));
        a1[c] = rdfl(fabsf(sharpness[(n0 + c) * 2 + 1]));
    }
    const float e = exponent[0];

    float acc[NPB];
#pragma unroll
    for (int c = 0; c < NPB; ++c) acc[c] = 0.0f;

    if (e == 1.0f) {
        const float4* bb4 = reinterpret_cast<const float4*>(batch)
                          + (size_t)b * (P / 2) + wave * 256;
        const float2* nd2 = reinterpret_cast<const float2*>(not_dummy)
                          + (size_t)b * (P / 2) + wave * 256;

        float4 xq[KQ];
        float2 wq[KQ];
#pragma unroll
        for (int k = 0; k < KQ; ++k) {
            xq[k] = bb4[k * 64 + lane];
            wq[k] = nd2[k * 64 + lane];
        }

#pragma unroll
        for (int c = 0; c < NPB; ++c) {
#pragma unroll
            for (int k = 0; k < KQ; ++k) {
                const float4 x = xq[k];
                const float2 w = wq[k];
                const float ua = fmaf(fabsf(c0[c] - x.x), a0[c],
                                  fmaf(fabsf(c1[c] - x.y), a1[c], 1.0f));
                const float ub = fmaf(fabsf(c0[c] - x.z), a0[c],
                                  fmaf(fabsf(c1[c] - x.w), a1[c], 1.0f));
                float num = w.x * ub;
                num = fmaf(w.y, ua, num);
                const float den = ua * ub;
                acc[c] = fmaf(num, __builtin_amdgcn_rcpf(den), acc[c]);
            }
        }
    } else {
        const float2* bb = reinterpret_cast<const float2*>(batch)
                         + (size_t)b * P + wave * 512;
        const float*  nd = not_dummy + (size_t)b * P + wave * 512;
        for (int it = 0; it < 8; ++it) {
            const int p = it * 64 + lane;
            const float2 x = bb[p];
            const float  w = nd[p];
#pragma unroll
            for (int c = 0; c < NPB; ++c) {
                const float s = fmaf(fabsf(c0[c] - x.x), a0[c],
                                     fabsf(c1[c] - x.y) * a1[c]);
                acc[c] += w / (1.0f + powf(s, e));
            }
        }
    }

    const bool lo = (lane < 32);
    float r[4];
#pragma unroll
    for (int j = 0; j < 4; ++j) {
        const float m = lo ? acc[j] : acc[j + 4];
        const float o = lo ? acc[j + 4] : acc[j];
        r[j] = m + __shfl_xor(o, 32, 64);
    }
#pragma unroll
    for (int j = 0; j < 4; ++j) {
#pragma unroll
        for (int off = 16; off > 0; off >>= 1)
            r[j] += __shfl_xor(r[j], off, 64);
    }

    __shared__ float red[4][NPB];
    if ((lane & 31) == 0) {
        float4* dst = reinterpret_cast<float4*>(&red[wave][(lane >> 5) * 4]);
        *dst = make_float4(r[0], r[1], r[2], r[3]);
    }
    __syncthreads();

    if (threadIdx.x < NPB) {
        const int t = threadIdx.x;
        out[b * N + n0 + t] = red[0][t] + red[1][t] + red[2][t] + red[3][t];
    }
}

// ------------- Kernel B: timing diagnostic, REP x inner work -------------
// Identical code footprint for every REP (rep loop NOT unrolled); inputs
// re-opaqued per rep via empty asm so reps cannot be CSE'd; lane-0 partials
// stored to d_ws so nothing is dead.
template<int REP>
__global__ __launch_bounds__(TPB, 8)
void slayer_diag_kernel(
    const float* __restrict__ batch,
    const float* __restrict__ not_dummy,
    const float* __restrict__ centers,
    const float* __restrict__ sharpness,
    const float* __restrict__ exponent,
    float* __restrict__ ws, size_t ws_off_elems, size_t ws_cap_bytes)
{
    const int b    = blockIdx.x >> 5;
    const int n0   = (blockIdx.x & 31) * NPB;
    const int wave = threadIdx.x >> 6;
    const int lane = threadIdx.x & 63;

    if (exponent[0] != 1.0f) return;   // diagnostic covers the taken path only

    float c0[NPB], c1[NPB], a0[NPB], a1[NPB];
#pragma unroll
    for (int c = 0; c < NPB; ++c) {
        c0[c] = rdfl(centers[(n0 + c) * 2 + 0]);
        c1[c] = rdfl(centers[(n0 + c) * 2 + 1]);
        a0[c] = rdfl(fabsf(sharpness[(n0 + c) * 2 + 0]));
        a1[c] = rdfl(fabsf(sharpness[(n0 + c) * 2 + 1]));
    }

    const float4* bb4 = reinterpret_cast<const float4*>(batch)
                      + (size_t)b * (P / 2) + wave * 256;
    const float2* nd2 = reinterpret_cast<const float2*>(not_dummy)
                      + (size_t)b * (P / 2) + wave * 256;

    float4 xq[KQ];
    float2 wq[KQ];
#pragma unroll
    for (int k = 0; k < KQ; ++k) {
        xq[k] = bb4[k * 64 + lane];
        wq[k] = nd2[k * 64 + lane];
    }

    float acc[NPB];
#pragma unroll
    for (int c = 0; c < NPB; ++c) acc[c] = 0.0f;

#pragma unroll 1
    for (int rep = 0; rep < REP; ++rep) {
#pragma unroll
        for (int k = 0; k < KQ; ++k) {
            asm volatile("" : "+v"(xq[k].x), "+v"(xq[k].y), "+v"(xq[k].z),
                              "+v"(xq[k].w), "+v"(wq[k].x), "+v"(wq[k].y));
        }
#pragma unroll
        for (int c = 0; c < NPB; ++c) {
#pragma unroll
            for (int k = 0; k < KQ; ++k) {
                const float4 x = xq[k];
                const float2 w = wq[k];
                const float ua = fmaf(fabsf(c0[c] - x.x), a0[c],
                                  fmaf(fabsf(c1[c] - x.y), a1[c], 1.0f));
                const float ub = fmaf(fabsf(c0[c] - x.z), a0[c],
                                  fmaf(fabsf(c1[c] - x.w), a1[c], 1.0f));
                float num = w.x * ub;
                num = fmaf(w.y, ua, num);
                const float den = ua * ub;
                acc[c] = fmaf(num, __builtin_amdgcn_rcpf(den), acc[c]);
            }
        }
    }

    if (lane == 0) {
        const size_t idx = ws_off_elems + ((size_t)blockIdx.x * 4 + wave) * NPB;
        if ((idx + NPB) * sizeof(float) <= ws_cap_bytes) {
#pragma unroll
            for (int c = 0; c < NPB; ++c) ws[idx + c] = acc[c];
        }
    }
}

extern "C" void kernel_launch(void* const* d_in, const int* in_sizes, int n_in,
                              void* d_out, int out_size, void* d_ws, size_t ws_size,
                              hipStream_t stream) {
    const float* batch     = (const float*)d_in[0];
    const float* not_dummy = (const float*)d_in[1];
    const float* centers   = (const float*)d_in[2];
    const float* sharpness = (const float*)d_in[3];
    const float* exponent  = (const float*)d_in[4];
    float* out = (float*)d_out;
    float* ws  = (float*)d_ws;

    const int blocks = B * (N / NPB);  // 4096

    // A: real output
    SLayerRational_43190191128606_kernel<<<blocks, TPB, 0, stream>>>(
        batch, not_dummy, centers, sharpness, exponent, out);

    // B1 / B4: work-scaling discriminator (same code, REP=1 vs REP=4)
    slayer_diag_kernel<1><<<blocks, TPB, 0, stream>>>(
        batch, not_dummy, centers, sharpness, exponent, ws, 0, ws_size);
    slayer_diag_kernel<4><<<blocks, TPB, 0, stream>>>(
        batch, not_dummy, centers, sharpness, exponent, ws, 131072, ws_size);
}

// Round 7
// 117.684 us; speedup vs baseline: 1.8019x; 1.8019x over previous
//
#include <hip/hip_runtime.h>

// Problem constants: B=128, P=2048, N=256, D=2
constexpr int B   = 128;
constexpr int P   = 2048;
constexpr int N   = 256;
constexpr int TPB = 256;   // 4 waves
constexpr int NPB = 8;     // centers per block
constexpr int KQ  = 4;     // float4 loads per lane = 8 points/lane

__device__ __forceinline__ float rdfl(float v) {
    return __int_as_float(__builtin_amdgcn_readfirstlane(__float_as_int(v)));
}

// ---------------- Kernel A: real output (R5 verbatim, 20.3 us) ----------------
__global__ __launch_bounds__(TPB, 8)
void SLayerRational_43190191128606_kernel(
    const float* __restrict__ batch,      // (B, P, 2)
    const float* __restrict__ not_dummy,  // (B, P)
    const float* __restrict__ centers,    // (N, 2)
    const float* __restrict__ sharpness,  // (N, 2)
    const float* __restrict__ exponent,   // (1,)
    float* __restrict__ out)              // (B, N)
{
    const int b    = blockIdx.x >> 5;
    const int n0   = (blockIdx.x & 31) * NPB;
    const int wave = threadIdx.x >> 6;
    const int lane = threadIdx.x & 63;

    float c0[NPB], c1[NPB], a0[NPB], a1[NPB];
#pragma unroll
    for (int c = 0; c < NPB; ++c) {
        c0[c] = rdfl(centers[(n0 + c) * 2 + 0]);
        c1[c] = rdfl(centers[(n0 + c) * 2 + 1]);
        a0[c] = rdfl(fabsf(sharpness[(n0 + c) * 2 + 0]));
        a1[c] = rdfl(fabsf(sharpness[(n0 + c) * 2 + 1]));
    }
    const float e = exponent[0];

    float acc[NPB];
#pragma unroll
    for (int c = 0; c < NPB; ++c) acc[c] = 0.0f;

    if (e == 1.0f) {
        const float4* bb4 = reinterpret_cast<const float4*>(batch)
                          + (size_t)b * (P / 2) + wave * 256;
        const float2* nd2 = reinterpret_cast<const float2*>(not_dummy)
                          + (size_t)b * (P / 2) + wave * 256;

        float4 xq[KQ];
        float2 wq[KQ];
#pragma unroll
        for (int k = 0; k < KQ; ++k) {
            xq[k] = bb4[k * 64 + lane];
            wq[k] = nd2[k * 64 + lane];
        }

#pragma unroll
        for (int c = 0; c < NPB; ++c) {
#pragma unroll
            for (int k = 0; k < KQ; ++k) {
                const float4 x = xq[k];
                const float2 w = wq[k];
                const float ua = fmaf(fabsf(c0[c] - x.x), a0[c],
                                  fmaf(fabsf(c1[c] - x.y), a1[c], 1.0f));
                const float ub = fmaf(fabsf(c0[c] - x.z), a0[c],
                                  fmaf(fabsf(c1[c] - x.w), a1[c], 1.0f));
                float num = w.x * ub;
                num = fmaf(w.y, ua, num);
                const float den = ua * ub;
                acc[c] = fmaf(num, __builtin_amdgcn_rcpf(den), acc[c]);
            }
        }
    } else {
        const float2* bb = reinterpret_cast<const float2*>(batch)
                         + (size_t)b * P + wave * 512;
        const float*  nd = not_dummy + (size_t)b * P + wave * 512;
        for (int it = 0; it < 8; ++it) {
            const int p = it * 64 + lane;
            const float2 x = bb[p];
            const float  w = nd[p];
#pragma unroll
            for (int c = 0; c < NPB; ++c) {
                const float s = fmaf(fabsf(c0[c] - x.x), a0[c],
                                     fabsf(c1[c] - x.y) * a1[c]);
                acc[c] += w / (1.0f + powf(s, e));
            }
        }
    }

    const bool lo = (lane < 32);
    float r[4];
#pragma unroll
    for (int j = 0; j < 4; ++j) {
        const float m = lo ? acc[j] : acc[j + 4];
        const float o = lo ? acc[j + 4] : acc[j];
        r[j] = m + __shfl_xor(o, 32, 64);
    }
#pragma unroll
    for (int j = 0; j < 4; ++j) {
#pragma unroll
        for (int off = 16; off > 0; off >>= 1)
            r[j] += __shfl_xor(r[j], off, 64);
    }

    __shared__ float red[4][NPB];
    if ((lane & 31) == 0) {
        float4* dst = reinterpret_cast<float4*>(&red[wave][(lane >> 5) * 4]);
        *dst = make_float4(r[0], r[1], r[2], r[3]);
    }
    __syncthreads();

    if (threadIdx.x < NPB) {
        const int t = threadIdx.x;
        out[b * N + n0 + t] = red[0][t] + red[1][t] + red[2][t] + red[3][t];
    }
}

// ---- Kernel S: work-scaling diagnostic. REP x A's inner work, NO asm, ----
// ---- no register-array reuse across reps (per-rep global loads, so   ----
// ---- addresses are loop-variant -> no CSE, no spill pressure).       ----
template<int REP>
__global__ __launch_bounds__(TPB, 8)
void slayer_scale_kernel(
    const float* __restrict__ batch,
    const float* __restrict__ not_dummy,
    const float* __restrict__ centers,
    const float* __restrict__ sharpness,
    const float* __restrict__ exponent,
    float* __restrict__ ws, size_t ws_cap_bytes)
{
    const int b    = blockIdx.x >> 5;
    const int n0   = (blockIdx.x & 31) * NPB;
    const int wave = threadIdx.x >> 6;
    const int lane = threadIdx.x & 63;

    float c0[NPB], c1[NPB], a0[NPB], a1[NPB];
#pragma unroll
    for (int c = 0; c < NPB; ++c) {
        c0[c] = rdfl(centers[(n0 + c) * 2 + 0]);
        c1[c] = rdfl(centers[(n0 + c) * 2 + 1]);
        a0[c] = rdfl(fabsf(sharpness[(n0 + c) * 2 + 0]));
        a1[c] = rdfl(fabsf(sharpness[(n0 + c) * 2 + 1]));
    }

    float acc[NPB];
#pragma unroll
    for (int c = 0; c < NPB; ++c) acc[c] = 0.0f;

    if (exponent[0] == 1.0f) {
        const float4* bbase = reinterpret_cast<const float4*>(batch) + (size_t)b * (P / 2);
        const float2* nbase = reinterpret_cast<const float2*>(not_dummy) + (size_t)b * (P / 2);

#pragma unroll 1
        for (int rep = 0; rep < REP; ++rep) {
            const int slice = (wave + rep) & 3;        // loop-variant address
            const float4* bb4 = bbase + slice * 256;
            const float2* nd2 = nbase + slice * 256;

            float4 xq[KQ];
            float2 wq[KQ];
#pragma unroll
            for (int k = 0; k < KQ; ++k) {
                xq[k] = bb4[k * 64 + lane];
                wq[k] = nd2[k * 64 + lane];
            }

#pragma unroll
            for (int c = 0; c < NPB; ++c) {
#pragma unroll
                for (int k = 0; k < KQ; ++k) {
                    const float4 x = xq[k];
                    const float2 w = wq[k];
                    const float ua = fmaf(fabsf(c0[c] - x.x), a0[c],
                                      fmaf(fabsf(c1[c] - x.y), a1[c], 1.0f));
                    const float ub = fmaf(fabsf(c0[c] - x.z), a0[c],
                                      fmaf(fabsf(c1[c] - x.w), a1[c], 1.0f));
                    float num = w.x * ub;
                    num = fmaf(w.y, ua, num);
                    const float den = ua * ub;
                    acc[c] = fmaf(num, __builtin_amdgcn_rcpf(den), acc[c]);
                }
            }
        }
    }

    if (lane == 0) {
        const size_t idx = ((size_t)blockIdx.x * 4 + wave) * NPB;
        if ((idx + NPB) * sizeof(float) <= ws_cap_bytes) {
#pragma unroll
            for (int c = 0; c < NPB; ++c) ws[idx + c] = acc[c];
        }
    }
}

extern "C" void kernel_launch(void* const* d_in, const int* in_sizes, int n_in,
                              void* d_out, int out_size, void* d_ws, size_t ws_size,
                              hipStream_t stream) {
    const float* batch     = (const float*)d_in[0];
    const float* not_dummy = (const float*)d_in[1];
    const float* centers   = (const float*)d_in[2];
    const float* sharpness = (const float*)d_in[3];
    const float* exponent  = (const float*)d_in[4];
    float* out = (float*)d_out;
    float* ws  = (float*)d_ws;

    const int blocks = B * (N / NPB);  // 4096

    // A: real output (unchanged, keeps bench green)
    SLayerRational_43190191128606_kernel<<<blocks, TPB, 0, stream>>>(
        batch, not_dummy, centers, sharpness, exponent, out);

    // S8: 8x inner work, spill-proof; its rocprof row is the readout.
    slayer_scale_kernel<8><<<blocks, TPB, 0, stream>>>(
        batch, not_dummy, centers, sharpness, exponent, ws, ws_size);
}

// Round 8
// 24.570 us; speedup vs baseline: 8.6306x; 4.7898x over previous
//
#include <hip/hip_runtime.h>
#include <hip/hip_fp16.h>

// Problem constants: B=128, P=2048, N=256, D=2
constexpr int B   = 128;
constexpr int P   = 2048;
constexpr int N   = 256;
constexpr int TPB = 256;   // 4 waves
constexpr int NPB = 16;    // centers per block -> 2048 blocks = exactly 1 round
constexpr int KQ  = 4;     // float4 loads per lane = 8 points = 4 packed pairs

__device__ __forceinline__ float rdfl(float v) {
    return __int_as_float(__builtin_amdgcn_readfirstlane(__float_as_int(v)));
}
__device__ __forceinline__ __half2 rdfl2(__half2 v) {
    union { __half2 h; int i; } u;
    u.h = v;
    u.i = __builtin_amdgcn_readfirstlane(u.i);
    return u.h;
}

__global__ __launch_bounds__(TPB, 8)   // 64-VGPR budget; est. ~48
void SLayerRational_43190191128606_kernel(
    const float* __restrict__ batch,      // (B, P, 2)
    const float* __restrict__ not_dummy,  // (B, P)
    const float* __restrict__ centers,    // (N, 2)
    const float* __restrict__ sharpness,  // (N, 2)
    const float* __restrict__ exponent,   // (1,)
    float* __restrict__ out)              // (B, N)
{
    const int b    = blockIdx.x >> 4;          // N/NPB = 16 tiles per row
    const int n0   = (blockIdx.x & 15) * NPB;
    const int wave = threadIdx.x >> 6;
    const int lane = threadIdx.x & 63;

    const float e = exponent[0];

    float acc[NPB];

    if (e == 1.0f) {
        // ---- Packed-f16 fast path: 9 issue slots per 2 points per center ----
        // Wave-uniform params as broadcast half2 in SGPRs.
        __half2 C0[NPB], C1[NPB], A0[NPB], A1[NPB];
#pragma unroll
        for (int c = 0; c < NPB; ++c) {
            C0[c] = rdfl2(__float2half2_rn(centers[(n0 + c) * 2 + 0]));
            C1[c] = rdfl2(__float2half2_rn(centers[(n0 + c) * 2 + 1]));
            A0[c] = rdfl2(__float2half2_rn(fabsf(sharpness[(n0 + c) * 2 + 0])));
            A1[c] = rdfl2(__float2half2_rn(fabsf(sharpness[(n0 + c) * 2 + 1])));
        }

        // Wave slice: 512 points; lane holds 8 points = 4 packed pairs.
        const float4* bb4 = reinterpret_cast<const float4*>(batch)
                          + (size_t)b * (P / 2) + wave * 256;
        const float2* nd2 = reinterpret_cast<const float2*>(not_dummy)
                          + (size_t)b * (P / 2) + wave * 256;

        // Load + deinterleave-convert: X0=(xa.x,xb.x), X1=(xa.y,xb.y), W=(wa,wb)
        __half2 X0[KQ], X1[KQ], W[KQ];
#pragma unroll
        for (int k = 0; k < KQ; ++k) {
            const float4 x = bb4[k * 64 + lane];
            const float2 w = nd2[k * 64 + lane];
            X0[k] = __floats2half2_rn(x.x, x.z);
            X1[k] = __floats2half2_rn(x.y, x.w);
            W[k]  = __floats2half2_rn(w.x, w.y);
        }

        const __half2 one2 = __float2half2_rn(1.0f);

#pragma unroll
        for (int c = 0; c < NPB; ++c) {
            __half2 ah = __float2half2_rn(0.0f);   // spans only 8 points: <= 8.0
#pragma unroll
            for (int k = 0; k < KQ; ++k) {
                const __half2 d0 = __hsub2(C0[c], X0[k]);
                const __half2 d1 = __hsub2(C1[c], X1[k]);
                const __half2 u  = __hfma2(__habs2(d0), A0[c],
                                   __hfma2(__habs2(d1), A1[c], one2));
                ah = __hfma2(W[k], h2rcp(u), ah);
            }
            acc[c] = __low2float(ah) + __high2float(ah);  // fold to fp32 per center
        }
    } else {
        // ---- General path: fp32, r = w / (1 + s^e), direct loads ----
        float c0[NPB], c1[NPB], a0[NPB], a1[NPB];
#pragma unroll
        for (int c = 0; c < NPB; ++c) {
            c0[c] = rdfl(centers[(n0 + c) * 2 + 0]);
            c1[c] = rdfl(centers[(n0 + c) * 2 + 1]);
            a0[c] = rdfl(fabsf(sharpness[(n0 + c) * 2 + 0]));
            a1[c] = rdfl(fabsf(sharpness[(n0 + c) * 2 + 1]));
        }
#pragma unroll
        for (int c = 0; c < NPB; ++c) acc[c] = 0.0f;

        const float2* bb = reinterpret_cast<const float2*>(batch)
                         + (size_t)b * P + wave * 512;
        const float*  nd = not_dummy + (size_t)b * P + wave * 512;
        for (int it = 0; it < 8; ++it) {
            const int p = it * 64 + lane;
            const float2 x = bb[p];
            const float  w = nd[p];
#pragma unroll
            for (int c = 0; c < NPB; ++c) {
                const float s = fmaf(fabsf(c0[c] - x.x), a0[c],
                                     fabsf(c1[c] - x.y) * a1[c]);
                acc[c] += w / (1.0f + powf(s, e));
            }
        }
    }

    // ---- Reduction: fold 16 accs -> 8 regs across 32-lane halves ----
    // lanes<32 carry centers 0..7, lanes>=32 carry centers 8..15
    const bool lo = (lane < 32);
    float r[8];
#pragma unroll
    for (int j = 0; j < 8; ++j) {
        const float m = lo ? acc[j] : acc[j + 8];
        const float o = lo ? acc[j + 8] : acc[j];
        r[j] = m + __shfl_xor(o, 32, 64);
    }
#pragma unroll
    for (int j = 0; j < 8; ++j) {
#pragma unroll
        for (int off = 16; off > 0; off >>= 1)
            r[j] += __shfl_xor(r[j], off, 64);
    }

    // Cross-wave combine: two float4 LDS writes per half-wave leader.
    __shared__ float red[4][NPB];
    if ((lane & 31) == 0) {
        float4* dst = reinterpret_cast<float4*>(&red[wave][(lane >> 5) * 8]);
        dst[0] = make_float4(r[0], r[1], r[2], r[3]);
        dst[1] = make_float4(r[4], r[5], r[6], r[7]);
    }
    __syncthreads();

    if (threadIdx.x < NPB) {
        const int t = threadIdx.x;
        out[b * N + n0 + t] = red[0][t] + red[1][t] + red[2][t] + red[3][t];
    }
}

extern "C" void kernel_launch(void* const* d_in, const int* in_sizes, int n_in,
                              void* d_out, int out_size, void* d_ws, size_t ws_size,
                              hipStream_t stream) {
    const float* batch     = (const float*)d_in[0];
    const float* not_dummy = (const float*)d_in[1];
    const float* centers   = (const float*)d_in[2];
    const float* sharpness = (const float*)d_in[3];
    const float* exponent  = (const float*)d_in[4];
    float* out = (float*)d_out;

    const int blocks = B * (N / NPB);  // 2048 -> exactly 8 waves/SIMD, 1 round
    SLayerRational_43190191128606_kernel<<<blocks, TPB, 0, stream>>>(
        batch, not_dummy, centers, sharpness, exponent, out);
}

// Round 10
// 22.476 us; speedup vs baseline: 9.4347x; 1.0932x over previous
//
#include <hip/hip_runtime.h>

// Problem constants: B=128, P=2048, N=256, D=2
constexpr int B   = 128;
constexpr int P   = 2048;
constexpr int N   = 256;
constexpr int TPB = 256;   // 4 waves
constexpr int NPB = 16;    // centers per block -> 2048 blocks = 1 full round
constexpr int KQ  = 4;     // float4 loads per lane = 8 points/lane

typedef _Float16 half2_t __attribute__((ext_vector_type(2)));

__device__ __forceinline__ float rdfl(float v) {
    return __int_as_float(__builtin_amdgcn_readfirstlane(__float_as_int(v)));
}
__device__ __forceinline__ half2_t rdfl_h2(half2_t v) {
    int i = __builtin_bit_cast(int, v);
    i = __builtin_amdgcn_readfirstlane(i);
    return __builtin_bit_cast(half2_t, i);
}
__device__ __forceinline__ half2_t habs2(half2_t v) {
    int i = __builtin_bit_cast(int, v) & 0x7fff7fff;
    return __builtin_bit_cast(half2_t, i);
}
// pack two f32 -> f16x2 (round toward zero); bit-cast the __fp16 vector result
__device__ __forceinline__ half2_t pk_h2(float a, float b) {
    return __builtin_bit_cast(half2_t, __builtin_amdgcn_cvt_pkrtz(a, b));
}
// u = |d| . A + 1.0  (one v_dot2_f32_f16 when available; fp32 accumulate)
__device__ __forceinline__ float dist_u(half2_t dabs, half2_t A) {
#if __has_builtin(__builtin_amdgcn_fdot2)
    return __builtin_amdgcn_fdot2(dabs, A, 1.0f, false);
#else
    return fmaf((float)dabs.x, (float)A.x,
                fmaf((float)dabs.y, (float)A.y, 1.0f));
#endif
}

__global__ __launch_bounds__(TPB, 8)   // 64-VGPR budget; est. ~50
void SLayerRational_43190191128606_kernel(
    const float* __restrict__ batch,      // (B, P, 2)
    const float* __restrict__ not_dummy,  // (B, P)
    const float* __restrict__ centers,    // (N, 2)
    const float* __restrict__ sharpness,  // (N, 2)
    const float* __restrict__ exponent,   // (1,)
    float* __restrict__ out)              // (B, N)
{
    const int b    = blockIdx.x >> 4;          // N/NPB = 16 tiles per row
    const int n0   = (blockIdx.x & 15) * NPB;
    const int wave = threadIdx.x >> 6;
    const int lane = threadIdx.x & 63;

    const float e = exponent[0];

    float acc[NPB];
#pragma unroll
    for (int c = 0; c < NPB; ++c) acc[c] = 0.0f;

    if (e == 1.0f) {
        // ---- fdot2 fast path: distances in f16, rcp/accum in fp32 ----
        // Wave-uniform packed params -> SGPRs (converted once).
        half2_t C[NPB], A[NPB];
#pragma unroll
        for (int c = 0; c < NPB; ++c) {
            half2_t t;
            t.x = (_Float16)centers[(n0 + c) * 2 + 0];
            t.y = (_Float16)centers[(n0 + c) * 2 + 1];
            C[c] = rdfl_h2(t);
            t.x = (_Float16)fabsf(sharpness[(n0 + c) * 2 + 0]);
            t.y = (_Float16)fabsf(sharpness[(n0 + c) * 2 + 1]);
            A[c] = rdfl_h2(t);
        }

        // Wave slice: 512 points; lane holds 8 points.
        const float4* bb4 = reinterpret_cast<const float4*>(batch)
                          + (size_t)b * (P / 2) + wave * 256;
        const float2* nd2 = reinterpret_cast<const float2*>(not_dummy)
                          + (size_t)b * (P / 2) + wave * 256;

        half2_t X[2 * KQ];   // packed (x,y) per point
        float   wf[2 * KQ];  // fp32 weights
#pragma unroll
        for (int k = 0; k < KQ; ++k) {
            const float4 x = bb4[k * 64 + lane];
            const float2 w = nd2[k * 64 + lane];
            X[2 * k]     = pk_h2(x.x, x.y);
            X[2 * k + 1] = pk_h2(x.z, x.w);
            wf[2 * k]     = w.x;
            wf[2 * k + 1] = w.y;
        }

        // Per center: 2 quads of 4 points, one fp32 rcp per quad.
        //   sum_i w_i/u_i = [(w0 u1 + w1 u0) p23 + (w2 u3 + w3 u2) p01] / (p01 p23)
#pragma unroll
        for (int c = 0; c < NPB; ++c) {
#pragma unroll
            for (int q = 0; q < 2; ++q) {
                const int base = q * 4;
                const float u0 = dist_u(habs2(C[c] - X[base + 0]), A[c]);
                const float u1 = dist_u(habs2(C[c] - X[base + 1]), A[c]);
                const float u2 = dist_u(habs2(C[c] - X[base + 2]), A[c]);
                const float u3 = dist_u(habs2(C[c] - X[base + 3]), A[c]);
                const float p01 = u0 * u1;
                const float p23 = u2 * u3;
                const float den = p01 * p23;
                float t0 = wf[base + 0] * u1;
                t0 = fmaf(wf[base + 1], u0, t0);
                float t1 = wf[base + 2] * u3;
                t1 = fmaf(wf[base + 3], u2, t1);
                float num = t0 * p23;
                num = fmaf(t1, p01, num);
                acc[c] = fmaf(num, __builtin_amdgcn_rcpf(den), acc[c]);
            }
        }
    } else {
        // ---- General path: fp32, r = w / (1 + s^e), direct loads ----
        float c0[NPB], c1[NPB], a0[NPB], a1[NPB];
#pragma unroll
        for (int c = 0; c < NPB; ++c) {
            c0[c] = rdfl(centers[(n0 + c) * 2 + 0]);
            c1[c] = rdfl(centers[(n0 + c) * 2 + 1]);
            a0[c] = rdfl(fabsf(sharpness[(n0 + c) * 2 + 0]));
            a1[c] = rdfl(fabsf(sharpness[(n0 + c) * 2 + 1]));
        }
        const float2* bb = reinterpret_cast<const float2*>(batch)
                         + (size_t)b * P + wave * 512;
        const float*  nd = not_dummy + (size_t)b * P + wave * 512;
        for (int it = 0; it < 8; ++it) {
            const int p = it * 64 + lane;
            const float2 x = bb[p];
            const float  w = nd[p];
#pragma unroll
            for (int c = 0; c < NPB; ++c) {
                const float s = fmaf(fabsf(c0[c] - x.x), a0[c],
                                     fabsf(c1[c] - x.y) * a1[c]);
                acc[c] += w / (1.0f + powf(s, e));
            }
        }
    }

    // ---- Reduction: fold 16 accs -> 8 regs across 32-lane halves ----
    const bool lo = (lane < 32);
    float r[8];
#pragma unroll
    for (int j = 0; j < 8; ++j) {
        const float m = lo ? acc[j] : acc[j + 8];
        const float o = lo ? acc[j + 8] : acc[j];
        r[j] = m + __shfl_xor(o, 32, 64);
    }
#pragma unroll
    for (int j = 0; j < 8; ++j) {
#pragma unroll
        for (int off = 16; off > 0; off >>= 1)
            r[j] += __shfl_xor(r[j], off, 64);
    }

    // Cross-wave combine: two float4 LDS writes per half-wave leader.
    __shared__ float red[4][NPB];
    if ((lane & 31) == 0) {
        float4* dst = reinterpret_cast<float4*>(&red[wave][(lane >> 5) * 8]);
        dst[0] = make_float4(r[0], r[1], r[2], r[3]);
        dst[1] = make_float4(r[4], r[5], r[6], r[7]);
    }
    __syncthreads();

    if (threadIdx.x < NPB) {
        const int t = threadIdx.x;
        out[b * N + n0 + t] = red[0][t] + red[1][t] + red[2][t] + red[3][t];
    }
}

extern "C" void kernel_launch(void* const* d_in, const int* in_sizes, int n_in,
                              void* d_out, int out_size, void* d_ws, size_t ws_size,
                              hipStream_t stream) {
    const float* batch     = (const float*)d_in[0];
    const float* not_dummy = (const float*)d_in[1];
    const float* centers   = (const float*)d_in[2];
    const float* sharpness = (const float*)d_in[3];
    const float* exponent  = (const float*)d_in[4];
    float* out = (float*)d_out;

    const int blocks = B * (N / NPB);  // 2048 -> exactly 8 waves/SIMD, 1 round
    SLayerRational_43190191128606_kernel<<<blocks, TPB, 0, stream>>>(
        batch, not_dummy, centers, sharpness, exponent, out);
}

// Round 11
// 21.883 us; speedup vs baseline: 9.6904x; 1.0271x over previous
//
#include <hip/hip_runtime.h>

// Problem constants: B=128, P=2048, N=256, D=2
constexpr int B   = 128;
constexpr int P   = 2048;
constexpr int N   = 256;
constexpr int TPB = 256;   // 4 waves
constexpr int NPB = 16;    // centers per block -> 2048 blocks = 1 full round
constexpr int KQ  = 4;     // float4 loads per lane = 8 points/lane

__device__ __forceinline__ float rdfl(float v) {
    return __int_as_float(__builtin_amdgcn_readfirstlane(__float_as_int(v)));
}

__global__ __launch_bounds__(TPB, 8)   // 64-VGPR budget; est. ~48
void SLayerRational_43190191128606_kernel(
    const float* __restrict__ batch,      // (B, P, 2)
    const float* __restrict__ not_dummy,  // (B, P)
    const float* __restrict__ centers,    // (N, 2)
    const float* __restrict__ sharpness,  // (N, 2)
    const float* __restrict__ exponent,   // (1,)
    float* __restrict__ out)              // (B, N)
{
    const int b    = blockIdx.x >> 4;          // N/NPB = 16 tiles per row
    const int n0   = (blockIdx.x & 15) * NPB;
    const int wave = threadIdx.x >> 6;
    const int lane = threadIdx.x & 63;

    const float e = exponent[0];

    float acc[NPB];
#pragma unroll
    for (int c = 0; c < NPB; ++c) acc[c] = 0.0f;

    if (e == 1.0f) {
        // ---- fp32 fast path: quad-rcp (one v_rcp_f32 per 4 points) ----
        // Wave-uniform params -> SGPRs.
        float c0[NPB], c1[NPB], a0[NPB], a1[NPB];
#pragma unroll
        for (int c = 0; c < NPB; ++c) {
            c0[c] = rdfl(centers[(n0 + c) * 2 + 0]);
            c1[c] = rdfl(centers[(n0 + c) * 2 + 1]);
            a0[c] = rdfl(fabsf(sharpness[(n0 + c) * 2 + 0]));
            a1[c] = rdfl(fabsf(sharpness[(n0 + c) * 2 + 1]));
        }

        // Wave slice: 512 points; lane holds 8 points, register-resident.
        const float4* bb4 = reinterpret_cast<const float4*>(batch)
                          + (size_t)b * (P / 2) + wave * 256;
        const float2* nd2 = reinterpret_cast<const float2*>(not_dummy)
                          + (size_t)b * (P / 2) + wave * 256;

        float4 xq[KQ];
        float2 wq[KQ];
#pragma unroll
        for (int k = 0; k < KQ; ++k) {
            xq[k] = bb4[k * 64 + lane];
            wq[k] = nd2[k * 64 + lane];
        }

        // Per center: 2 quads of 4 points, one fp32 rcp per quad.
        //   sum_i w_i/u_i = [(w0 u1 + w1 u0) p23 + (w2 u3 + w3 u2) p01] / (p01 p23)
        // u = 1 + |c0-x| a0 + |c1-y| a1  (sub, sub, fma(abs), fma(abs))
#pragma unroll
        for (int c = 0; c < NPB; ++c) {
#pragma unroll
            for (int q = 0; q < 2; ++q) {
                const float4 xA = xq[2 * q];
                const float4 xB = xq[2 * q + 1];
                const float2 wA = wq[2 * q];
                const float2 wB = wq[2 * q + 1];
                const float u0 = fmaf(fabsf(c0[c] - xA.x), a0[c],
                                  fmaf(fabsf(c1[c] - xA.y), a1[c], 1.0f));
                const float u1 = fmaf(fabsf(c0[c] - xA.z), a0[c],
                                  fmaf(fabsf(c1[c] - xA.w), a1[c], 1.0f));
                const float u2 = fmaf(fabsf(c0[c] - xB.x), a0[c],
                                  fmaf(fabsf(c1[c] - xB.y), a1[c], 1.0f));
                const float u3 = fmaf(fabsf(c0[c] - xB.z), a0[c],
                                  fmaf(fabsf(c1[c] - xB.w), a1[c], 1.0f));
                const float p01 = u0 * u1;
                const float p23 = u2 * u3;
                const float den = p01 * p23;
                float t0 = wA.x * u1;
                t0 = fmaf(wA.y, u0, t0);
                float t1 = wB.x * u3;
                t1 = fmaf(wB.y, u2, t1);
                float num = t0 * p23;
                num = fmaf(t1, p01, num);
                acc[c] = fmaf(num, __builtin_amdgcn_rcpf(den), acc[c]);
            }
        }
    } else {
        // ---- General path: fp32, r = w / (1 + s^e), direct loads ----
        float c0[NPB], c1[NPB], a0[NPB], a1[NPB];
#pragma unroll
        for (int c = 0; c < NPB; ++c) {
            c0[c] = rdfl(centers[(n0 + c) * 2 + 0]);
            c1[c] = rdfl(centers[(n0 + c) * 2 + 1]);
            a0[c] = rdfl(fabsf(sharpness[(n0 + c) * 2 + 0]));
            a1[c] = rdfl(fabsf(sharpness[(n0 + c) * 2 + 1]));
        }
        const float2* bb = reinterpret_cast<const float2*>(batch)
                         + (size_t)b * P + wave * 512;
        const float*  nd = not_dummy + (size_t)b * P + wave * 512;
        for (int it = 0; it < 8; ++it) {
            const int p = it * 64 + lane;
            const float2 x = bb[p];
            const float  w = nd[p];
#pragma unroll
            for (int c = 0; c < NPB; ++c) {
                const float s = fmaf(fabsf(c0[c] - x.x), a0[c],
                                     fabsf(c1[c] - x.y) * a1[c]);
                acc[c] += w / (1.0f + powf(s, e));
            }
        }
    }

    // ---- Reduction: fold 16 accs -> 8 regs across 32-lane halves ----
    const bool lo = (lane < 32);
    float r[8];
#pragma unroll
    for (int j = 0; j < 8; ++j) {
        const float m = lo ? acc[j] : acc[j + 8];
        const float o = lo ? acc[j + 8] : acc[j];
        r[j] = m + __shfl_xor(o, 32, 64);
    }
#pragma unroll
    for (int j = 0; j < 8; ++j) {
#pragma unroll
        for (int off = 16; off > 0; off >>= 1)
            r[j] += __shfl_xor(r[j], off, 64);
    }

    // Cross-wave combine: two float4 LDS writes per half-wave leader.
    __shared__ float red[4][NPB];
    if ((lane & 31) == 0) {
        float4* dst = reinterpret_cast<float4*>(&red[wave][(lane >> 5) * 8]);
        dst[0] = make_float4(r[0], r[1], r[2], r[3]);
        dst[1] = make_float4(r[4], r[5], r[6], r[7]);
    }
    __syncthreads();

    if (threadIdx.x < NPB) {
        const int t = threadIdx.x;
        out[b * N + n0 + t] = red[0][t] + red[1][t] + red[2][t] + red[3][t];
    }
}

extern "C" void kernel_launch(void* const* d_in, const int* in_sizes, int n_in,
                              void* d_out, int out_size, void* d_ws, size_t ws_size,
                              hipStream_t stream) {
    const float* batch     = (const float*)d_in[0];
    const float* not_dummy = (const float*)d_in[1];
    const float* centers   = (const float*)d_in[2];
    const float* sharpness = (const float*)d_in[3];
    const float* exponent  = (const float*)d_in[4];
    float* out = (float*)d_out;

    const int blocks = B * (N / NPB);  // 2048 -> 8 waves/SIMD, single round
    SLayerRational_43190191128606_kernel<<<blocks, TPB, 0, stream>>>(
        batch, not_dummy, centers, sharpness, exponent, out);
}

// Round 12
// 19.356 us; speedup vs baseline: 10.9554x; 1.1305x over previous
//
#include <hip/hip_runtime.h>

// Problem constants: B=128, P=2048, N=256, D=2
// R4 geometry (best measured: 19.58 us): 1024 blocks x 4 waves, each wave
// owns 8 centers, full row register-resident per lane (32 points).
constexpr int B   = 128;
constexpr int P   = 2048;
constexpr int N   = 256;
constexpr int TPB = 256;     // 4 waves
constexpr int CPW = 8;       // centers per wave
constexpr int NPB = 32;      // centers per block = 4 waves * 8
constexpr int HV  = 16;      // float4 loads per lane (2 points each -> 32 pts/lane)

__device__ __forceinline__ float rdfl(float v) {
    return __int_as_float(__builtin_amdgcn_readfirstlane(__float_as_int(v)));
}

__global__ __launch_bounds__(TPB, 4)   // 128-VGPR budget
void SLayerRational_43190191128606_kernel(
    const float* __restrict__ batch,      // (B, P, 2)
    const float* __restrict__ not_dummy,  // (B, P)
    const float* __restrict__ centers,    // (N, 2)
    const float* __restrict__ sharpness,  // (N, 2)
    const float* __restrict__ exponent,   // (1,)
    float* __restrict__ out)              // (B, N)
{
    const int b    = blockIdx.x >> 3;          // N/NPB = 8 tiles per batch row
    const int n0   = (blockIdx.x & 7) * NPB;
    const int wave = threadIdx.x >> 6;
    const int lane = threadIdx.x & 63;
    const int nw   = n0 + wave * CPW;

    // Wave-uniform center params -> SGPRs
    float c0[CPW], c1[CPW], a0[CPW], a1[CPW];
#pragma unroll
    for (int c = 0; c < CPW; ++c) {
        c0[c] = rdfl(centers[(nw + c) * 2 + 0]);
        c1[c] = rdfl(centers[(nw + c) * 2 + 1]);
        a0[c] = rdfl(fabsf(sharpness[(nw + c) * 2 + 0]));
        a1[c] = rdfl(fabsf(sharpness[(nw + c) * 2 + 1]));
    }
    const float e = exponent[0];

    float acc[CPW];
#pragma unroll
    for (int c = 0; c < CPW; ++c) acc[c] = 0.0f;

    if (e == 1.0f) {
        // ---- Fast path: row register-resident, ALL indices compile-time ----
        // Lane loads 16 float4 (= 32 points' xy) + 16 float2 (= 32 weights).
        const float4* bb4 = reinterpret_cast<const float4*>(batch) + (size_t)b * (P / 2);
        const float2* nd2 = reinterpret_cast<const float2*>(not_dummy) + (size_t)b * (P / 2);

        float4 xq[HV];
        float2 wq[HV];
#pragma unroll
        for (int k = 0; k < HV; ++k) {
            xq[k] = bb4[k * 64 + lane];
            wq[k] = nd2[k * 64 + lane];
        }

        // Steady state: pure register VALU.
#pragma unroll
        for (int c = 0; c < CPW; ++c) {
#pragma unroll
            for (int k = 0; k < HV; ++k) {
                const float4 x = xq[k];
                const float2 w = wq[k];
                const float ua = fmaf(fabsf(c0[c] - x.x), a0[c],
                                  fmaf(fabsf(c1[c] - x.y), a1[c], 1.0f));
                acc[c] = fmaf(w.x, __builtin_amdgcn_rcpf(ua), acc[c]);
                const float ub = fmaf(fabsf(c0[c] - x.z), a0[c],
                                  fmaf(fabsf(c1[c] - x.w), a1[c], 1.0f));
                acc[c] = fmaf(w.y, __builtin_amdgcn_rcpf(ub), acc[c]);
            }
        }
    } else {
        // ---- General path: r = w / (1 + s^e); direct global loads, no arrays ----
        const float2* bb = reinterpret_cast<const float2*>(batch) + (size_t)b * P;
        const float*  nd = not_dummy + (size_t)b * P;
        for (int it = 0; it < P / 64; ++it) {
            const int p = it * 64 + lane;
            const float2 x = bb[p];
            const float  w = nd[p];
#pragma unroll
            for (int c = 0; c < CPW; ++c) {
                const float s = fmaf(fabsf(c0[c] - x.x), a0[c],
                                     fabsf(c1[c] - x.y) * a1[c]);
                acc[c] += w / (1.0f + powf(s, e));
            }
        }
    }

    // Wave-local tree reduction; no LDS, no __syncthreads.
#pragma unroll
    for (int c = 0; c < CPW; ++c) {
#pragma unroll
        for (int off = 32; off > 0; off >>= 1)
            acc[c] += __shfl_down(acc[c], off, 64);
    }

    if (lane == 0) {
#pragma unroll
        for (int c = 0; c < CPW; ++c)
            out[b * N + nw + c] = acc[c];
    }
}

extern "C" void kernel_launch(void* const* d_in, const int* in_sizes, int n_in,
                              void* d_out, int out_size, void* d_ws, size_t ws_size,
                              hipStream_t stream) {
    const float* batch     = (const float*)d_in[0];
    const float* not_dummy = (const float*)d_in[1];
    const float* centers   = (const float*)d_in[2];
    const float* sharpness = (const float*)d_in[3];
    const float* exponent  = (const float*)d_in[4];
    float* out = (float*)d_out;

    const int blocks = B * (N / NPB);  // 1024
    SLayerRational_43190191128606_kernel<<<blocks, TPB, 0, stream>>>(
        batch, not_dummy, centers, sharpness, exponent, out);
}